// Round 21
// baseline (417.827 us; speedup 1.0000x reference)
//
#include <hip/hip_runtime.h>

// blockDim 256 = FOUR wave64s. wave = tid>>6 ∈ {0,1,2,3}.

typedef __bf16 bf16_t;
typedef __bf16 bf16x8 __attribute__((ext_vector_type(8)));
typedef __bf16 bf16x4 __attribute__((ext_vector_type(4)));
typedef float  f32x4  __attribute__((ext_vector_type(4)));

#define MFMA16(a,b,c) __builtin_amdgcn_mfma_f32_16x16x32_bf16((a),(b),(c),0,0,0)

constexpr int NNODES = 32768;
constexpr int NEDGES = 262144;
constexpr int DD = 128;
constexpr int HH = 256;

__device__ __forceinline__ bf16x8 cvt8(f32x4 a, f32x4 b){
  bf16x8 r;
  r[0]=(bf16_t)a[0]; r[1]=(bf16_t)a[1]; r[2]=(bf16_t)a[2]; r[3]=(bf16_t)a[3];
  r[4]=(bf16_t)b[0]; r[5]=(bf16_t)b[1]; r[6]=(bf16_t)b[2]; r[7]=(bf16_t)b[3];
  return r;
}

// ---- merged weight packs: blocks 0-127 wpb, 128-143 wcb (tile order), 144-159 wn2b (tile order)
__global__ void pack_weights_kernel(const float* __restrict__ Wm1, const float* __restrict__ Wr1,
                                    const float* __restrict__ Wn2,
                                    bf16_t* __restrict__ wp, bf16_t* __restrict__ wc,
                                    bf16_t* __restrict__ wn2){
  const int bx = blockIdx.x;
  const int tid = threadIdx.x;
  if (bx < 128){
    int idx = (bx*256 + tid)*4;
    int n = idx >> 7, k = idx & 127;
    const float* W = (n < 512) ? Wm1 : Wr1;
    int row = n & 255;
    int colbase = ((n >> 8) & 1) * 128;
    f32x4 v = *(const f32x4*)(W + (size_t)row*320 + colbase + k);
    bf16x4 o; o[0]=(bf16_t)v[0]; o[1]=(bf16_t)v[1]; o[2]=(bf16_t)v[2]; o[3]=(bf16_t)v[3];
    *(bf16x4*)(wp + idx) = o;
  } else if (bx < 144){
    int g = (bx-128)*256 + tid;            // < 4096; parts of 2048 groups = 16384 elems
    int part = g >> 11, gg = g & 2047;
    int tile = gg >> 6, lane = gg & 63;
    int kc = tile >> 4, nt = tile & 15;
    int lr = lane & 15, lk = lane >> 4;
    const float* W = part ? Wr1 : Wm1;
    int row = nt*16 + lr;
    int col = 256 + kc*32 + lk*8;
    f32x4 v0 = *(const f32x4*)(W + (size_t)row*320 + col);
    f32x4 v1 = *(const f32x4*)(W + (size_t)row*320 + col + 4);
    *(bf16x8*)(wc + (size_t)g*8) = cvt8(v0,v1);
  } else {
    int g = (bx-144)*256 + tid;            // < 4096
    int tile = g >> 6, lane = g & 63;
    int kc = tile >> 3, nt = tile & 7;
    int lr = lane & 15, lk = lane >> 4;
    int row = nt*16 + lr;
    int col = kc*32 + lk*8;
    f32x4 v0 = *(const f32x4*)(Wn2 + (size_t)row*256 + col);
    f32x4 v1 = *(const f32x4*)(Wn2 + (size_t)row*256 + col + 4);
    *(bf16x8*)(wn2 + (size_t)g*8) = cvt8(v0,v1);
  }
}

// ---------------- CSR build (atomics only) ----------------
__global__ void hist_kernel(const int* __restrict__ to_idx, const int* __restrict__ from_idx,
                            int* __restrict__ cnt_to, int* __restrict__ cnt_from){
  int e = blockIdx.x*256 + threadIdx.x;
  if (e < NEDGES){
    atomicAdd(&cnt_to[to_idx[e]], 1);
    atomicAdd(&cnt_from[from_idx[e]], 1);
  }
}

// grid 2: block 0 scans cnt_to, block 1 scans cnt_from
__global__ void scan_kernel(int* __restrict__ cnt_to, int* __restrict__ cnt_from,
                            int* __restrict__ start_to, int* __restrict__ start_from){
  int* cnt   = blockIdx.x ? cnt_from : cnt_to;
  int* start = blockIdx.x ? start_from : start_to;
  __shared__ int sums[1024];
  const int t = threadIdx.x;
  int local[32]; int s = 0;
  #pragma unroll
  for (int j=0;j<32;j++){ local[j] = cnt[t*32+j]; s += local[j]; }
  sums[t] = s; __syncthreads();
  #pragma unroll
  for (int d=1; d<1024; d<<=1){
    int v = (t>=d) ? sums[t-d] : 0;
    __syncthreads();
    sums[t] += v;
    __syncthreads();
  }
  int off = sums[t] - s;
  #pragma unroll
  for (int j=0;j<32;j++){
    start[t*32+j] = off;
    cnt[t*32+j]   = off;
    off += local[j];
  }
  if (t == 1023) start[32768] = sums[1023];
}

__global__ void place_kernel(const int* __restrict__ to_idx, const int* __restrict__ from_idx,
                             int* __restrict__ cur_to, int* __restrict__ cur_from,
                             int* __restrict__ eid_to, int* __restrict__ eid_from,
                             int* __restrict__ rowv_to, int* __restrict__ rowv_from){
  int e = blockIdx.x*256 + threadIdx.x;
  if (e < NEDGES){
    int vt = to_idx[e];
    int p = atomicAdd(&cur_to[vt], 1);
    eid_to[p] = e;
    rowv_to[p] = vt;
    int vf = from_idx[e];
    int q = atomicAdd(&cur_from[vf], 1);
    eid_from[q] = e;
    rowv_from[q] = vf;
  }
}

// ---------------- node projections, both dirs: P = ns @ Wblock^T (K=128) ----------------
// grid (512, 2): y = dir. Each block computes BOTH cb halves, staging ns once.
// P2 gets +b1 folded in.
__global__ __launch_bounds__(256,3) void proj_kernel(
    const float* __restrict__ ns, const bf16_t* __restrict__ Wp,
    const float* __restrict__ bm1, const float* __restrict__ br1,
    bf16_t* __restrict__ P1f, bf16_t* __restrict__ P2f,
    bf16_t* __restrict__ P1r, bf16_t* __restrict__ P2r)
{
  constexpr int XS = 136;
  constexpr int CS = 264;
  __shared__ bf16_t Xs[64*XS];
  __shared__ bf16_t Cs[64*CS];
  const int tid = threadIdx.x;
  const int rb = blockIdx.x*64;
  const int dir = blockIdx.y;
  const float* bvec = dir ? br1 : bm1;
  #pragma unroll
  for (int it=0; it<8; ++it){
    int c = tid + it*256;
    int row = c >> 5, co = (c & 31)*4;
    f32x4 v = *(const f32x4*)(ns + (size_t)(rb+row)*DD + co);
    bf16x4 o; o[0]=(bf16_t)v[0]; o[1]=(bf16_t)v[1]; o[2]=(bf16_t)v[2]; o[3]=(bf16_t)v[3];
    *(bf16x4*)&Xs[row*XS + co] = o;
  }
  __syncthreads();
  const int lane = tid & 63, wave = tid >> 6, lr = lane & 15, lk = lane >> 4;
  for (int cb=0; cb<2; ++cb){
    const bf16_t* Wb = Wp + (size_t)(dir*2 + cb)*32768;   // wpb part stride = 256*128
    f32x4 acc[16];
    #pragma unroll
    for (int nt=0;nt<16;nt++) acc[nt] = (f32x4){0.f,0.f,0.f,0.f};
    #pragma unroll
    for (int kc=0;kc<4;kc++){
      bf16x8 a = *(const bf16x8*)&Xs[(wave*16 + lr)*XS + kc*32 + lk*8];
      #pragma unroll
      for (int nt=0;nt<16;nt++){
        bf16x8 b = *(const bf16x8*)&Wb[(size_t)(nt*16 + lr)*128 + kc*32 + lk*8];
        acc[nt] = MFMA16(a,b,acc[nt]);
      }
    }
    #pragma unroll
    for (int nt=0;nt<16;nt++){
      const float bias = cb ? bvec[nt*16 + lr] : 0.f;   // fold b1 into P2
      #pragma unroll
      for (int r=0;r<4;r++)
        Cs[(wave*16 + lk*4 + r)*CS + nt*16 + lr] = (bf16_t)(acc[nt][r] + bias);
    }
    __syncthreads();
    bf16_t* P = dir ? (cb ? P2r : P1r) : (cb ? P2f : P1f);
    #pragma unroll
    for (int it=0; it<8; ++it){
      int c = tid + it*256;
      int row = c >> 5, co = (c & 31)*8;
      *(bf16x8*)&P[(size_t)(rb+row)*HH + co] = *(const bf16x8*)&Cs[row*CS + co];
    }
    __syncthreads();   // Cs reuse guard for next cb
  }
}

// ---------------- FUSED edge projection + combine + segmented aggregate, both dirs ----------------
// grid 8192: dir = bx>>12, rb = (bx&4095)*64. A-operand gathered from f32 ef (proven round 16).
// Partials are TILE-indexed: each node spans <=2 tiles (deg << 64).
__global__ __launch_bounds__(256,4) void edge_agg_kernel(
    const float* __restrict__ ef, const bf16_t* __restrict__ Wc,
    const int* __restrict__ eid_to, const int* __restrict__ eid_from,
    const int* __restrict__ from_idx, const int* __restrict__ to_idx,
    const int* __restrict__ rowv_to, const int* __restrict__ rowv_from,
    const int* __restrict__ start_to, const int* __restrict__ start_from,
    const bf16_t* __restrict__ P1f, const bf16_t* __restrict__ P2f,
    const bf16_t* __restrict__ P1r, const bf16_t* __restrict__ P2r,
    bf16_t* __restrict__ partial_f, bf16_t* __restrict__ partial_r,
    bf16_t* __restrict__ aggh_f, bf16_t* __restrict__ aggh_r)
{
  constexpr int CS = 264;
  __shared__ bf16_t Cs[64*CS];
  __shared__ int es[64], os[64], vs[64];
  const int tid = threadIdx.x;
  const int dir = blockIdx.x >> 12;
  const int tile = blockIdx.x & 4095;
  const int rb = tile*64;
  const int* eid  = dir ? eid_from  : eid_to;
  const int* oth  = dir ? to_idx    : from_idx;
  const int* rowv = dir ? rowv_from : rowv_to;
  const int* start= dir ? start_from: start_to;
  const bf16_t* P1 = dir ? P1r : P1f;
  const bf16_t* P2 = dir ? P2r : P2f;
  bf16_t* partial  = dir ? partial_r : partial_f;
  bf16_t* aggh     = dir ? aggh_r : aggh_f;
  const bf16_t* Wcd = Wc + (size_t)dir*16384;   // wcb part stride = 256*64 = 16384 elems

  if (tid < 64){
    int e = eid[rb + tid];
    es[tid] = e;
    os[tid] = oth[e];
    vs[tid] = rowv[rb + tid];
  }
  __syncthreads();

  const int lane = tid & 63, wave = tid >> 6, lr = lane & 15, lk = lane >> 4;
  {
    const float* arow = ef + (size_t)es[wave*16 + lr]*64;
    bf16x8 a0, a1;
    {
      f32x4 v0 = *(const f32x4*)(arow + lk*8);
      f32x4 v1 = *(const f32x4*)(arow + lk*8 + 4);
      a0 = cvt8(v0,v1);
      f32x4 w0 = *(const f32x4*)(arow + 32 + lk*8);
      f32x4 w1 = *(const f32x4*)(arow + 32 + lk*8 + 4);
      a1 = cvt8(w0,w1);
    }
    #pragma unroll
    for (int p=0;p<2;p++){
      f32x4 acc[8];
      #pragma unroll
      for (int nt=0;nt<8;nt++) acc[nt] = (f32x4){0.f,0.f,0.f,0.f};
      #pragma unroll
      for (int nt=0;nt<8;nt++){
        bf16x8 b0 = *(const bf16x8*)&Wcd[(size_t)((0*16 + p*8 + nt)*64 + lane)*8];
        acc[nt] = MFMA16(a0,b0,acc[nt]);
        bf16x8 b1v = *(const bf16x8*)&Wcd[(size_t)((1*16 + p*8 + nt)*64 + lane)*8];
        acc[nt] = MFMA16(a1,b1v,acc[nt]);
      }
      #pragma unroll
      for (int nt=0;nt<8;nt++)
        #pragma unroll
        for (int r=0;r<4;r++)
          Cs[(wave*16 + lk*4 + r)*CS + (p*8+nt)*16 + lr] = (bf16_t)acc[nt][r];
    }
  }
  __syncthreads();

  // phase 2a: vectorized branchless combine+relu (b1 already inside P2)
  const int c8 = (tid & 31) * 8;
  const int rbase = (tid >> 5) * 8;
  {
    #pragma unroll
    for (int j=0;j<8;j++){
      const int row = rbase + j;
      bf16x8 cs = *(const bf16x8*)&Cs[row*CS + c8];
      bf16x8 p1 = *(const bf16x8*)&P1[(size_t)os[row]*HH + c8];
      bf16x8 p2 = *(const bf16x8*)&P2[(size_t)vs[row]*HH + c8];
      bf16x8 o;
      #pragma unroll
      for (int k=0;k<8;k++)
        o[k] = (bf16_t)fmaxf((float)cs[k] + (float)p1[k] + (float)p2[k], 0.f);
      *(bf16x8*)&Cs[row*CS + c8] = o;
    }
  }
  __syncthreads();

  // phase 2b: LDS-only segmented sum (branch is block-uniform); tile-indexed partials
  const int c = tid;
  float runsum = 0.f;
  int curv = vs[0];
  for (int row=0; row<64; ++row){
    const int v = vs[row];
    if (v != curv){
      const int s0 = start[curv], s1 = start[curv+1];
      if (s0 >= rb && s1 <= rb+64)
        aggh[(size_t)curv*HH + c] = (bf16_t)runsum;
      else
        partial[((size_t)tile*2 + (s0 >= rb ? 1 : 0))*HH + c] = (bf16_t)runsum;
      runsum = 0.f; curv = v;
    }
    runsum += (float)Cs[row*CS + c];
  }
  {
    const int s0 = start[curv], s1 = start[curv+1];
    if (s0 >= rb && s1 <= rb+64)
      aggh[(size_t)curv*HH + c] = (bf16_t)runsum;
    else
      partial[((size_t)tile*2 + (s0 >= rb ? 1 : 0))*HH + c] = (bf16_t)runsum;
  }
}

// boundary node v (spans tiles t0,t0+1): aggh[v] = partial[t0][1] + partial[t0+1][0].
// deg-0: aggh[v]=0. grid (4096, 2): y=dir.
__global__ __launch_bounds__(256) void combine_kernel(
    const bf16_t* __restrict__ partial_f, const bf16_t* __restrict__ partial_r,
    const int* __restrict__ start_to, const int* __restrict__ start_from,
    bf16_t* __restrict__ aggh_f, bf16_t* __restrict__ aggh_r)
{
  const int dir = blockIdx.y;
  const bf16_t* partial = dir ? partial_r : partial_f;
  const int* start = dir ? start_from : start_to;
  bf16_t* aggh = dir ? aggh_r : aggh_f;
  const int tid = threadIdx.x;
  const int v = blockIdx.x*8 + (tid>>5);
  const int c0 = (tid & 31)*8;
  const int s0 = start[v], s1 = start[v+1];
  if (s1 == s0){
    bf16x8 z;
    #pragma unroll
    for (int j=0;j<8;j++) z[j] = (bf16_t)0.f;
    *(bf16x8*)&aggh[(size_t)v*HH + c0] = z;
  } else if ((s0>>6) != ((s1-1)>>6)){
    const int t0 = s0 >> 6;
    bf16x8 a = *(const bf16x8*)&partial[((size_t)t0*2 + 1)*HH + c0];
    bf16x8 b = *(const bf16x8*)&partial[((size_t)(t0+1)*2 + 0)*HH + c0];
    bf16x8 o;
    #pragma unroll
    for (int j=0;j<8;j++) o[j] = (bf16_t)((float)a[j] + (float)b[j]);
    *(bf16x8*)&aggh[(size_t)v*HH + c0] = o;
  }
}

// ---------------- weight prep for fused node MLP: w2t (blocks 0-31) + uw (block 32) ----------------
__global__ __launch_bounds__(256) void w2t_uw_kernel(const float* __restrict__ Wm2, const float* __restrict__ Wr2,
                                                     bf16_t* __restrict__ wm2T, bf16_t* __restrict__ wr2T,
                                                     const float* __restrict__ Wn1,
                                                     const float* __restrict__ bm2, const float* __restrict__ br2,
                                                     float* __restrict__ u, float* __restrict__ w){
  if (blockIdx.x == 32){
    const int n = threadIdx.x;
    float su=0.f, sw=0.f;
    for (int j=0;j<256;j+=4){
      f32x4 wv = *(const f32x4*)(Wn1 + (size_t)n*512 + j);
      f32x4 bu = *(const f32x4*)(bm2 + j);
      f32x4 bw = *(const f32x4*)(br2 + j);
      #pragma unroll
      for (int q=0;q<4;q++){ su += wv[q]*bu[q]; sw += wv[q]*bw[q]; }
    }
    u[n]=su; w[n]=sw;
    return;
  }
  __shared__ bf16_t t[64][72];
  const int bi = (blockIdx.x & 3)*64;
  const int bj = ((blockIdx.x>>2) & 3)*64;
  const int m  = blockIdx.x >> 4;
  const float* W = m ? Wr2 : Wm2;
  bf16_t* WT = m ? wr2T : wm2T;
  const int tid = threadIdx.x;
  #pragma unroll
  for (int it=0; it<16; ++it){
    int c = tid + it*256;
    int r = c >> 6, co = c & 63;
    t[r][co] = (bf16_t)W[(size_t)(bi+r)*256 + bj + co];
  }
  __syncthreads();
  #pragma unroll
  for (int it=0; it<16; ++it){
    int c = tid + it*256;
    int r = c >> 6, co = c & 63;
    WT[(size_t)(bj+r)*256 + bi + co] = t[co][r];
  }
}

// wcat: grid (4,3). cb<2: GEMM halves (proven). cb==2: copy Wn1[:,256:512] in tile order.
__global__ __launch_bounds__(256,2) void wcat_gemm_kernel(
    const float* __restrict__ Wn1, const bf16_t* __restrict__ wm2T, const bf16_t* __restrict__ wr2T,
    bf16_t* __restrict__ wcat)
{
  constexpr int XS = 264, CS = 264;
  const int tid = threadIdx.x;
  const int cb = blockIdx.y;
  if (cb == 2){
    #pragma unroll
    for (int it=0; it<8; ++it){
      int g = blockIdx.x*2048 + it*256 + tid;   // 8192 groups total
      int tile = g >> 6, lane = g & 63;
      int kc = tile >> 4, nt = tile & 15;
      int lr = lane & 15, lk = lane >> 4;
      int row = nt*16 + lr;
      int col = 256 + kc*32 + lk*8;
      f32x4 v0 = *(const f32x4*)(Wn1 + (size_t)row*512 + col);
      f32x4 v1 = *(const f32x4*)(Wn1 + (size_t)row*512 + col + 4);
      *(bf16x8*)&wcat[(size_t)(((16 + kc)*16 + nt)*64 + lane)*8] = cvt8(v0,v1);
    }
    return;
  }
  __shared__ bf16_t Xs[64*XS];
  __shared__ bf16_t Cs[64*CS];
  const int rb = blockIdx.x*64;
  const bf16_t* BT = cb ? wr2T : wm2T;
  #pragma unroll
  for (int it=0; it<16; ++it){
    int c = tid + it*256;
    int row = c >> 6, co = (c & 63)*4;
    f32x4 v = *(const f32x4*)(Wn1 + (size_t)(rb+row)*512 + co);
    bf16x4 o; o[0]=(bf16_t)v[0]; o[1]=(bf16_t)v[1]; o[2]=(bf16_t)v[2]; o[3]=(bf16_t)v[3];
    *(bf16x4*)&Xs[row*XS + co] = o;
  }
  __syncthreads();
  const int lane = tid & 63, wave = tid >> 6, lr = lane & 15, lk = lane >> 4;
  f32x4 acc[16];
  #pragma unroll
  for (int nt=0;nt<16;nt++) acc[nt] = (f32x4){0.f,0.f,0.f,0.f};
  #pragma unroll
  for (int kc=0;kc<8;kc++){
    bf16x8 a = *(const bf16x8*)&Xs[(wave*16 + lr)*XS + kc*32 + lk*8];
    #pragma unroll
    for (int nt=0;nt<16;nt++){
      bf16x8 b = *(const bf16x8*)&BT[(size_t)(nt*16 + lr)*256 + kc*32 + lk*8];
      acc[nt] = MFMA16(a,b,acc[nt]);
    }
  }
  #pragma unroll
  for (int nt=0;nt<16;nt++)
    #pragma unroll
    for (int r=0;r<4;r++)
      Cs[(wave*16 + lk*4 + r)*CS + nt*16 + lr] = (bf16_t)acc[nt][r];
  __syncthreads();
  const int nt_base = rb >> 4;
  #pragma unroll
  for (int it=0; it<8; ++it){
    int g = tid + it*256;
    int tile = g >> 6, lane2 = g & 63;
    int kc_l = tile >> 2, nt_l = tile & 3;
    int lr2 = lane2 & 15, lk2 = lane2 >> 4;
    bf16x8 v = *(const bf16x8*)&Cs[(nt_l*16 + lr2)*CS + kc_l*32 + lk2*8];
    *(bf16x8*)&wcat[(size_t)(((cb*8 + kc_l)*16 + nt_base + nt_l)*64 + lane2)*8] = v;
  }
}

// ---------------- nsT + nsB (proven round 14) ----------------
__global__ __launch_bounds__(256) void nst_kernel(const float* __restrict__ ns,
                                                  bf16_t* __restrict__ nsT,
                                                  bf16_t* __restrict__ nsB){
  constexpr int XS2 = 136;
  __shared__ bf16_t Xs[64*XS2];
  const int tid = threadIdx.x;
  const int nb = blockIdx.x*64;
  #pragma unroll
  for (int it=0; it<8; ++it){
    int c = tid + it*256;
    int rowl = c >> 5, co = (c & 31)*4;
    f32x4 v = *(const f32x4*)(ns + (size_t)(nb+rowl)*DD + co);
    bf16x4 o; o[0]=(bf16_t)v[0]; o[1]=(bf16_t)v[1]; o[2]=(bf16_t)v[2]; o[3]=(bf16_t)v[3];
    *(bf16x4*)&Xs[rowl*XS2 + co] = o;
    *(bf16x4*)&nsB[(size_t)(nb+rowl)*DD + co] = o;
  }
  __syncthreads();
  const int sb = nb >> 11;
  const int jb = nb & 2047;
  bf16_t* outp = nsT + (size_t)sb*DD*2048 + jb;
  #pragma unroll
  for (int it=0; it<4; ++it){
    int c = tid + it*256;
    int d = c >> 3, g8 = (c & 7)*8;
    bf16x8 o;
    #pragma unroll
    for (int k=0;k<8;k++){
      int s64 = g8 + k;
      int t32 = s64 >> 5, s = s64 & 31;
      int m = (s & 1) ? (16 + (s>>1)) : (s>>1);
      o[k] = Xs[(t32*32 + m)*XS2 + d];
    }
    *(bf16x8*)(outp + (size_t)d*2048 + g8) = o;
  }
}

// ---------------- cross-graph attention, KV-split (proven round 14; bf16 Opart; setprio) ----------------
__global__ __launch_bounds__(256,3) void attn_kernel(
    const bf16_t* __restrict__ nsB, const bf16_t* __restrict__ nsT,
    bf16_t* __restrict__ Opart, float* __restrict__ lpart)
{
  constexpr int KS = 136;
  constexpr int VS = 40;
  constexpr int PS = 40;
  __shared__ bf16_t Ks[2][32*KS];
  __shared__ bf16_t Vt[2][128*VS];
  __shared__ bf16_t Ps[64*PS];
  const int tid = threadIdx.x;
  const int lane = tid & 63, wave = tid >> 6, lr = lane & 15, lk = lane >> 4;
  const int bx = blockIdx.x;
  const int qt = bx & 31, side = (bx>>5)&1, p = (bx>>6)&7, kvh = bx>>9;
  const size_t qbase = (size_t)p*4096 + (size_t)side*2048 + (size_t)qt*64;
  const int sbkv = p*2 + (side^1);
  const bf16_t* Kv = nsB + ((size_t)p*4096 + (size_t)(side^1)*2048)*DD + (size_t)kvh*32*32*DD;
  const bf16_t* Vp = nsT + (size_t)sbkv*DD*2048 + (size_t)kvh*32*32;

  bf16x8 qf[4];
  {
    const bf16_t* qrow = nsB + (qbase + wave*16 + lr)*DD;
    #pragma unroll
    for (int kc=0;kc<4;kc++) qf[kc] = *(const bf16x8*)(qrow + kc*32 + lk*8);
  }
  float ls[4] = {0.f,0.f,0.f,0.f};
  f32x4 acco[8];
  #pragma unroll
  for (int nt=0;nt<8;nt++) acco[nt]=(f32x4){0.f,0.f,0.f,0.f};

  const int krow0 = tid>>4,        kcol = (tid&15)*8;
  const int vd0   = tid>>2,        vsl  = (tid&3)*8;
  bf16x8 kreg0, kreg1, vreg0, vreg1;

  auto load_tile = [&](int t){
    const bf16_t* kp = Kv + (size_t)t*32*DD;
    kreg0 = *(const bf16x8*)(kp + (size_t)krow0*DD + kcol);
    kreg1 = *(const bf16x8*)(kp + (size_t)(krow0+16)*DD + kcol);
    const bf16_t* vp = Vp + t*32;
    vreg0 = *(const bf16x8*)(vp + (size_t)vd0*2048 + vsl);
    vreg1 = *(const bf16x8*)(vp + (size_t)(vd0+64)*2048 + vsl);
  };
  auto store_tile = [&](int b){
    *(bf16x8*)&Ks[b][krow0*KS + kcol]      = kreg0;
    *(bf16x8*)&Ks[b][(krow0+16)*KS + kcol] = kreg1;
    *(bf16x8*)&Vt[b][vd0*VS + vsl]         = vreg0;
    *(bf16x8*)&Vt[b][(vd0+64)*VS + vsl]    = vreg1;
  };

  load_tile(0);
  store_tile(0);
  load_tile(1);
  __syncthreads();
  int cur = 0;
  for (int t=0; t<32; ++t){
    if (t+1 < 32){
      store_tile(cur^1);
      if (t+2 < 32) load_tile(t+2);
    }
    f32x4 s0 = (f32x4){0.f,0.f,0.f,0.f}, s1 = (f32x4){0.f,0.f,0.f,0.f};
    __builtin_amdgcn_s_setprio(1);
    #pragma unroll
    for (int kc=0;kc<4;kc++){
      bf16x8 b0 = *(const bf16x8*)&Ks[cur][lr*KS      + kc*32 + lk*8];
      bf16x8 b1 = *(const bf16x8*)&Ks[cur][(16+lr)*KS + kc*32 + lk*8];
      s0 = MFMA16(qf[kc], b0, s0);
      s1 = MFMA16(qf[kc], b1, s1);
    }
    __builtin_amdgcn_s_setprio(0);
    #pragma unroll
    for (int r=0;r<4;r++){
      float p0 = __expf(s0[r] - 40.f);
      float p1 = __expf(s1[r] - 40.f);
      ls[r] += p0 + p1;
      union { bf16_t h[2]; unsigned u; } pk;
      pk.h[0] = (bf16_t)p0; pk.h[1] = (bf16_t)p1;
      *(unsigned*)&Ps[(wave*16 + lk*4 + r)*PS + 2*lr] = pk.u;
    }
    asm volatile("s_waitcnt lgkmcnt(0)" ::: "memory");
    __builtin_amdgcn_sched_barrier(0);
    bf16x8 pa = *(const bf16x8*)&Ps[(wave*16 + lr)*PS + lk*8];
    __builtin_amdgcn_s_setprio(1);
    #pragma unroll
    for (int nt=0;nt<8;nt++){
      bf16x8 vb = *(const bf16x8*)&Vt[cur][(nt*16+lr)*VS + lk*8];
      acco[nt] = MFMA16(pa, vb, acco[nt]);
    }
    __builtin_amdgcn_s_setprio(0);
    __syncthreads();
    cur ^= 1;
  }
  #pragma unroll
  for (int r=0;r<4;r++){
    float v = ls[r];
    v += __shfl_xor(v,1); v += __shfl_xor(v,2);
    v += __shfl_xor(v,4); v += __shfl_xor(v,8);
    ls[r] = v;
  }
  bf16_t* Op = Opart + (size_t)kvh*NNODES*DD;
  #pragma unroll
  for (int r=0;r<4;r++){
    const size_t row = qbase + wave*16 + lk*4 + r;
    if (lr == 0) lpart[(size_t)kvh*NNODES + row] = ls[r];
    #pragma unroll
    for (int nt=0;nt<8;nt++)
      Op[row*DD + nt*16 + lr] = (bf16_t)acco[nt][r];
  }
}

// attnB = ns - (O0+O1)/(l0+l1)   (Opart stored bf16; O renormalized so 2^-8 rel err is fine)
__global__ __launch_bounds__(256) void attn_combine_kernel(
    const float* __restrict__ ns, const bf16_t* __restrict__ Opart,
    const float* __restrict__ lpart, bf16_t* __restrict__ attnB)
{
  const int tid = threadIdx.x;
  const int row = blockIdx.x*16 + (tid >> 4);
  const int c0 = (tid & 15)*8;
  const float inv = 1.f/(lpart[row] + lpart[NNODES + row]);
  bf16x8 a = *(const bf16x8*)&Opart[(size_t)row*DD + c0];
  bf16x8 b = *(const bf16x8*)&Opart[(size_t)NNODES*DD + (size_t)row*DD + c0];
  const float* nr = ns + (size_t)row*DD + c0;
  f32x4 n0 = *(const f32x4*)nr,      n1 = *(const f32x4*)(nr+4);
  bf16x8 o;
  #pragma unroll
  for (int j=0;j<4;j++){
    o[j]   = (bf16_t)(n0[j] - ((float)a[j]+(float)b[j])*inv);
    o[4+j] = (bf16_t)(n1[j] - ((float)a[4+j]+(float)b[4+j])*inv);
  }
  *(bf16x8*)&attnB[(size_t)row*DD + c0] = o;
}

// ---------------- fused node MLP + residual (proven round 9/13; 2 blocks/CU) ----------------
__global__ __launch_bounds__(256,2) void node_mlp_kernel(
    const bf16_t* __restrict__ agghf, const bf16_t* __restrict__ agghr,
    const bf16_t* __restrict__ attnB, const bf16_t* __restrict__ nsB,
    const float* __restrict__ ns,
    const bf16_t* __restrict__ wcat, const float* __restrict__ bn1,
    const float* __restrict__ uvec, const float* __restrict__ wvec,
    const int* __restrict__ start_to, const int* __restrict__ start_from,
    const bf16_t* __restrict__ Wn2b, const float* __restrict__ bn2,
    float* __restrict__ out)
{
  __shared__ __align__(16) bf16_t As[32*768];
  bf16_t* Hs = As;
  const int tid = threadIdx.x;
  const int lane = tid & 63, wave = tid >> 6, lr = lane & 15, lk = lane >> 4;
  const int rb = blockIdx.x*32;

  bf16x8 stg[12];
  int dsta[12];
  #pragma unroll
  for (int it=0; it<12; ++it){
    const int db = it*4096 + tid*16;
    const int row = db / 1536;
    const int within = db - row*1536;
    const size_t node = (size_t)(rb + row);
    const char* s0 = (const char*)agghf + (node<<9) + within;
    const char* s1 = (const char*)agghr + (node<<9) + (within-512);
    const char* s2 = (const char*)attnB + (node<<8) + (within-1024);
    const char* s3 = (const char*)nsB   + (node<<8) + (within-1280);
    const char* src = within < 512 ? s0 : (within < 1024 ? s1 : (within < 1280 ? s2 : s3));
    stg[it] = *(const bf16x8*)src;
    dsta[it] = row*1536 + (within ^ ((row & 7) << 4));
  }
  #pragma unroll
  for (int it=0; it<12; ++it)
    *(bf16x8*)((char*)As + dsta[it]) = stg[it];
  __syncthreads();

  const int cg = wave >> 1;
  const int colbase = cg * 128;
  const int arow = (wave & 1)*16 + lr;
  const unsigned abase = (unsigned)arow * 1536u;
  const unsigned asw = ((unsigned)(arow & 7)) << 4;
  f32x4 acc[8];
  #pragma unroll
  for (int nt=0;nt<8;nt++) acc[nt] = (f32x4){0.f,0.f,0.f,0.f};
  #pragma unroll
  for (int kc=0; kc<24; ++kc){
    const unsigned y = (unsigned)(kc*64 + lk*16);
    bf16x8 a = *(const bf16x8*)((const char*)As + abase + (y ^ asw));
    #pragma unroll
    for (int nt=0;nt<8;nt++){
      bf16x8 b = *(const bf16x8*)&wcat[(size_t)((kc*16 + cg*8 + nt)*64 + lane)*8];
      acc[nt] = MFMA16(a,b,acc[nt]);
    }
  }
  __syncthreads();

  const int r0 = rb + (wave&1)*16 + lk*4;
  float dt[4], df[4];
  #pragma unroll
  for (int r=0;r<4;r++){
    dt[r] = (float)(start_to[r0+r+1]   - start_to[r0+r]);
    df[r] = (float)(start_from[r0+r+1] - start_from[r0+r]);
  }
  #pragma unroll
  for (int nt=0;nt<8;nt++){
    const int col = colbase + nt*16 + lr;
    const float bias = bn1[col];
    const float uu = uvec[col], ww = wvec[col];
    #pragma unroll
    for (int r=0;r<4;r++){
      float v = acc[nt][r] + bias + dt[r]*uu + df[r]*ww;
      v = v > 0.f ? v : 0.f;
      Hs[((wave&1)*16 + lk*4 + r)*264 + col] = (bf16_t)v;
    }
  }
  __syncthreads();

  const int cb2 = cg * 64;
  f32x4 acc2[4];
  #pragma unroll
  for (int nt=0;nt<4;nt++) acc2[nt] = (f32x4){0.f,0.f,0.f,0.f};
  #pragma unroll
  for (int kc=0;kc<8;kc++){
    bf16x8 a = *(const bf16x8*)&Hs[((wave&1)*16 + lr)*264 + kc*32 + lk*8];
    #pragma unroll
    for (int nt=0;nt<4;nt++){
      bf16x8 b = *(const bf16x8*)&Wn2b[(size_t)((kc*8 + cg*4 + nt)*64 + lane)*8];
      acc2[nt] = MFMA16(a,b,acc2[nt]);
    }
  }
  #pragma unroll
  for (int nt=0;nt<4;nt++){
    const int col = cb2 + nt*16 + lr;
    const float bias = bn2[col];
    #pragma unroll
    for (int r=0;r<4;r++){
      const size_t rr = (size_t)(r0 + r);
      out[rr*DD + col] = acc2[nt][r] + bias + ns[rr*DD + col];
    }
  }
}

extern "C" void kernel_launch(void* const* d_in, const int* in_sizes, int n_in,
                              void* d_out, int out_size, void* d_ws, size_t ws_size,
                              hipStream_t stream) {
  const float* ns  = (const float*)d_in[0];
  const float* ef  = (const float*)d_in[1];
  const int* from_idx = (const int*)d_in[2];
  const int* to_idx   = (const int*)d_in[3];
  const float* Wm1 = (const float*)d_in[6];  const float* bm1 = (const float*)d_in[7];
  const float* Wm2 = (const float*)d_in[8];  const float* bm2 = (const float*)d_in[9];
  const float* Wr1 = (const float*)d_in[10]; const float* br1 = (const float*)d_in[11];
  const float* Wr2 = (const float*)d_in[12]; const float* br2 = (const float*)d_in[13];
  const float* Wn1 = (const float*)d_in[14]; const float* bn1 = (const float*)d_in[15];
  const float* Wn2 = (const float*)d_in[16]; const float* bn2 = (const float*)d_in[17];

  char* ws = (char*)d_ws;
  // ---- phase-1 region (0..134 MB) ----
  bf16_t* partial_f = (bf16_t*)(ws);                   // 4,194,304 (tile-indexed)
  bf16_t* partial_r = (bf16_t*)(ws + 4194304);         // 4,194,304 (ends 8,388,608)
  int*    rowv_to   = (int*)(ws + 41943040);           // 1 MB
  int*    rowv_from = (int*)(ws + 42991616);           // 1 MB (ends 44,040,192)
  bf16_t* P1r   = (bf16_t*)(ws + 44040192);            // 16,777,216
  bf16_t* P2r   = (bf16_t*)(ws + 60817408);            // 16,777,216 (ends 77,594,624)
  bf16_t* P1f   = (bf16_t*)(ws + 134217728);
  bf16_t* P2f   = (bf16_t*)(ws + 150994944);
  bf16_t* aggh_f = (bf16_t*)(ws + 167772160);
  bf16_t* aggh_r = (bf16_t*)(ws + 184549376);
  bf16_t* wpb  = (bf16_t*)(ws + 201326592);
  bf16_t* wcb  = (bf16_t*)(ws + 201588736);
  bf16_t* wn2b = (bf16_t*)(ws + 201654272);
  int* cur_to     = (int*)(ws + 202244096);
  int* cur_from   = (int*)(ws + 202375168);
  int* start_to   = (int*)(ws + 202506240);
  int* start_from = (int*)(ws + 202637320);
  int* eid_to     = (int*)(ws + 202768400);
  int* eid_from   = (int*)(ws + 203816976);
  // ---- phase-2 overlays (all producers run after combine; overlapped regions dead) ----
  bf16_t* attnB = (bf16_t*)(ws);                       // 8 MB over dead partials
  bf16_t* nsB   = (bf16_t*)(ws + 33554432);            // 8 MB
  bf16_t* nsT   = (bf16_t*)(ws + 41943040);            // 8 MB over dead rowv/P1r-head
  bf16_t* wm2T  = (bf16_t*)(ws + 50331648);            // 128 KB (dead P1r)
  bf16_t* wr2T  = (bf16_t*)(ws + 50462720);            // 128 KB
  bf16_t* wcat  = (bf16_t*)(ws + 50593792);            // 384 KB
  float*  uvec  = (float*) (ws + 50987008);            // 1 KB
  float*  wvec  = (float*) (ws + 50988032);            // 1 KB
  bf16_t* Opart = (bf16_t*)(ws + 69206016);            // 16 MB over dead P2r + free
  float*  lpart = (float*) (ws + 102760448);           // 256 KB

  hipMemsetAsync(cur_to, 0, 2*NNODES*sizeof(int), stream);

  pack_weights_kernel<<<160, 256, 0, stream>>>(Wm1, Wr1, Wn2, wpb, wcb, wn2b);

  hist_kernel<<<NEDGES/256, 256, 0, stream>>>(to_idx, from_idx, cur_to, cur_from);
  scan_kernel<<<2, 1024, 0, stream>>>(cur_to, cur_from, start_to, start_from);
  place_kernel<<<NEDGES/256, 256, 0, stream>>>(to_idx, from_idx, cur_to, cur_from,
      eid_to, eid_from, rowv_to, rowv_from);

  // both direction projections; each block computes both cb halves (ns staged once)
  proj_kernel<<<dim3(NNODES/64, 2), 256, 0, stream>>>(ns, wpb, bm1, br1,
      P1f, P2f, P1r, P2r);

  // both direction fused edge passes in one dispatch (f32 ef gather, in-kernel cvt)
  edge_agg_kernel<<<2*NEDGES/64, 256, 0, stream>>>(ef, wcb,
      eid_to, eid_from, from_idx, to_idx, rowv_to, rowv_from, start_to, start_from,
      P1f, P2f, P1r, P2r, partial_f, partial_r, aggh_f, aggh_r);

  combine_kernel<<<dim3(NNODES/8, 2), 256, 0, stream>>>(partial_f, partial_r,
      start_to, start_from, aggh_f, aggh_r);

  // phase 2 prep
  nst_kernel<<<NNODES/64, 256, 0, stream>>>(ns, nsT, nsB);
  w2t_uw_kernel<<<33, 256, 0, stream>>>(Wm2, Wr2, wm2T, wr2T, Wn1, bm2, br2, uvec, wvec);
  wcat_gemm_kernel<<<dim3(4,3), 256, 0, stream>>>(Wn1, wm2T, wr2T, wcat);

  attn_kernel<<<1024, 256, 0, stream>>>(nsB, nsT, Opart, lpart);
  attn_combine_kernel<<<NNODES/16, 256, 0, stream>>>(ns, Opart, lpart, attnB);

  node_mlp_kernel<<<NNODES/32, 256, 0, stream>>>(aggh_f, aggh_r, attnB, nsB, ns,
      wcat, bn1, uvec, wvec, start_to, start_from, wn2b, bn2, (float*)d_out);
}

// Round 22
// 407.479 us; speedup vs baseline: 1.0254x; 1.0254x over previous
//
#include <hip/hip_runtime.h>

// blockDim 256 = FOUR wave64s. wave = tid>>6 ∈ {0,1,2,3}.

typedef __bf16 bf16_t;
typedef __bf16 bf16x8 __attribute__((ext_vector_type(8)));
typedef __bf16 bf16x4 __attribute__((ext_vector_type(4)));
typedef float  f32x4  __attribute__((ext_vector_type(4)));

#define MFMA16(a,b,c) __builtin_amdgcn_mfma_f32_16x16x32_bf16((a),(b),(c),0,0,0)

constexpr int NNODES = 32768;
constexpr int NEDGES = 262144;
constexpr int DD = 128;
constexpr int HH = 256;

__device__ __forceinline__ bf16x8 cvt8(f32x4 a, f32x4 b){
  bf16x8 r;
  r[0]=(bf16_t)a[0]; r[1]=(bf16_t)a[1]; r[2]=(bf16_t)a[2]; r[3]=(bf16_t)a[3];
  r[4]=(bf16_t)b[0]; r[5]=(bf16_t)b[1]; r[6]=(bf16_t)b[2]; r[7]=(bf16_t)b[3];
  return r;
}

// ---- merged weight packs: blocks 0-127 wpb, 128-143 wcb (tile order), 144-159 wn2b (tile order)
__global__ void pack_weights_kernel(const float* __restrict__ Wm1, const float* __restrict__ Wr1,
                                    const float* __restrict__ Wn2,
                                    bf16_t* __restrict__ wp, bf16_t* __restrict__ wc,
                                    bf16_t* __restrict__ wn2){
  const int bx = blockIdx.x;
  const int tid = threadIdx.x;
  if (bx < 128){
    int idx = (bx*256 + tid)*4;
    int n = idx >> 7, k = idx & 127;
    const float* W = (n < 512) ? Wm1 : Wr1;
    int row = n & 255;
    int colbase = ((n >> 8) & 1) * 128;
    f32x4 v = *(const f32x4*)(W + (size_t)row*320 + colbase + k);
    bf16x4 o; o[0]=(bf16_t)v[0]; o[1]=(bf16_t)v[1]; o[2]=(bf16_t)v[2]; o[3]=(bf16_t)v[3];
    *(bf16x4*)(wp + idx) = o;
  } else if (bx < 144){
    int g = (bx-128)*256 + tid;            // < 4096; parts of 2048 groups = 16384 elems
    int part = g >> 11, gg = g & 2047;
    int tile = gg >> 6, lane = gg & 63;
    int kc = tile >> 4, nt = tile & 15;
    int lr = lane & 15, lk = lane >> 4;
    const float* W = part ? Wr1 : Wm1;
    int row = nt*16 + lr;
    int col = 256 + kc*32 + lk*8;
    f32x4 v0 = *(const f32x4*)(W + (size_t)row*320 + col);
    f32x4 v1 = *(const f32x4*)(W + (size_t)row*320 + col + 4);
    *(bf16x8*)(wc + (size_t)g*8) = cvt8(v0,v1);
  } else {
    int g = (bx-144)*256 + tid;            // < 4096
    int tile = g >> 6, lane = g & 63;
    int kc = tile >> 3, nt = tile & 7;
    int lr = lane & 15, lk = lane >> 4;
    int row = nt*16 + lr;
    int col = kc*32 + lk*8;
    f32x4 v0 = *(const f32x4*)(Wn2 + (size_t)row*256 + col);
    f32x4 v1 = *(const f32x4*)(Wn2 + (size_t)row*256 + col + 4);
    *(bf16x8*)(wn2 + (size_t)g*8) = cvt8(v0,v1);
  }
}

// ---------------- CSR build (atomics only) ----------------
__global__ void hist_kernel(const int* __restrict__ to_idx, const int* __restrict__ from_idx,
                            int* __restrict__ cnt_to, int* __restrict__ cnt_from){
  int e = blockIdx.x*256 + threadIdx.x;
  if (e < NEDGES){
    atomicAdd(&cnt_to[to_idx[e]], 1);
    atomicAdd(&cnt_from[from_idx[e]], 1);
  }
}

// grid 2: block 0 scans cnt_to, block 1 scans cnt_from
__global__ void scan_kernel(int* __restrict__ cnt_to, int* __restrict__ cnt_from,
                            int* __restrict__ start_to, int* __restrict__ start_from){
  int* cnt   = blockIdx.x ? cnt_from : cnt_to;
  int* start = blockIdx.x ? start_from : start_to;
  __shared__ int sums[1024];
  const int t = threadIdx.x;
  int local[32]; int s = 0;
  #pragma unroll
  for (int j=0;j<32;j++){ local[j] = cnt[t*32+j]; s += local[j]; }
  sums[t] = s; __syncthreads();
  #pragma unroll
  for (int d=1; d<1024; d<<=1){
    int v = (t>=d) ? sums[t-d] : 0;
    __syncthreads();
    sums[t] += v;
    __syncthreads();
  }
  int off = sums[t] - s;
  #pragma unroll
  for (int j=0;j<32;j++){
    start[t*32+j] = off;
    cnt[t*32+j]   = off;
    off += local[j];
  }
  if (t == 1023) start[32768] = sums[1023];
}

__global__ void place_kernel(const int* __restrict__ to_idx, const int* __restrict__ from_idx,
                             int* __restrict__ cur_to, int* __restrict__ cur_from,
                             int* __restrict__ eid_to, int* __restrict__ eid_from,
                             int* __restrict__ rowv_to, int* __restrict__ rowv_from){
  int e = blockIdx.x*256 + threadIdx.x;
  if (e < NEDGES){
    int vt = to_idx[e];
    int p = atomicAdd(&cur_to[vt], 1);
    eid_to[p] = e;
    rowv_to[p] = vt;
    int vf = from_idx[e];
    int q = atomicAdd(&cur_from[vf], 1);
    eid_from[q] = e;
    rowv_from[q] = vf;
  }
}

// ---------------- node projections, both dirs: P = ns @ Wblock^T (K=128) ----------------
// grid (512, 2, 2): y = cb (P1/P2), z = dir (fwd/rev). P2 gets +b1 folded in.
__global__ __launch_bounds__(256,3) void proj_kernel(
    const float* __restrict__ ns, const bf16_t* __restrict__ Wp,
    const float* __restrict__ bm1, const float* __restrict__ br1,
    bf16_t* __restrict__ P1f, bf16_t* __restrict__ P2f,
    bf16_t* __restrict__ P1r, bf16_t* __restrict__ P2r)
{
  constexpr int XS = 136;
  constexpr int CS = 264;
  __shared__ bf16_t Xs[64*XS];
  __shared__ bf16_t Cs[64*CS];
  const int tid = threadIdx.x;
  const int rb = blockIdx.x*64;
  const int cb = blockIdx.y;
  const int dir = blockIdx.z;
  const float* bvec = dir ? br1 : bm1;
  #pragma unroll
  for (int it=0; it<8; ++it){
    int c = tid + it*256;
    int row = c >> 5, co = (c & 31)*4;
    f32x4 v = *(const f32x4*)(ns + (size_t)(rb+row)*DD + co);
    bf16x4 o; o[0]=(bf16_t)v[0]; o[1]=(bf16_t)v[1]; o[2]=(bf16_t)v[2]; o[3]=(bf16_t)v[3];
    *(bf16x4*)&Xs[row*XS + co] = o;
  }
  __syncthreads();
  const int lane = tid & 63, wave = tid >> 6, lr = lane & 15, lk = lane >> 4;
  const bf16_t* Wb = Wp + (size_t)(dir*2 + cb)*32768;   // wpb part stride = 256*128
  f32x4 acc[16];
  #pragma unroll
  for (int nt=0;nt<16;nt++) acc[nt] = (f32x4){0.f,0.f,0.f,0.f};
  #pragma unroll
  for (int kc=0;kc<4;kc++){
    bf16x8 a = *(const bf16x8*)&Xs[(wave*16 + lr)*XS + kc*32 + lk*8];
    #pragma unroll
    for (int nt=0;nt<16;nt++){
      bf16x8 b = *(const bf16x8*)&Wb[(size_t)(nt*16 + lr)*128 + kc*32 + lk*8];
      acc[nt] = MFMA16(a,b,acc[nt]);
    }
  }
  #pragma unroll
  for (int nt=0;nt<16;nt++){
    const float bias = cb ? bvec[nt*16 + lr] : 0.f;   // fold b1 into P2
    #pragma unroll
    for (int r=0;r<4;r++)
      Cs[(wave*16 + lk*4 + r)*CS + nt*16 + lr] = (bf16_t)(acc[nt][r] + bias);
  }
  __syncthreads();
  bf16_t* P = dir ? (cb ? P2r : P1r) : (cb ? P2f : P1f);
  #pragma unroll
  for (int it=0; it<8; ++it){
    int c = tid + it*256;
    int row = c >> 5, co = (c & 31)*8;
    *(bf16x8*)&P[(size_t)(rb+row)*HH + co] = *(const bf16x8*)&Cs[row*CS + co];
  }
}

// ---------------- FUSED edge projection + combine + segmented aggregate, both dirs ----------------
// grid 8192: dir = bx>>12, rb = (bx&4095)*64. A-operand gathered from f32 ef (proven round 16).
// Partials are TILE-indexed: each node spans <=2 tiles (deg << 64).
__global__ __launch_bounds__(256,4) void edge_agg_kernel(
    const float* __restrict__ ef, const bf16_t* __restrict__ Wc,
    const int* __restrict__ eid_to, const int* __restrict__ eid_from,
    const int* __restrict__ from_idx, const int* __restrict__ to_idx,
    const int* __restrict__ rowv_to, const int* __restrict__ rowv_from,
    const int* __restrict__ start_to, const int* __restrict__ start_from,
    const bf16_t* __restrict__ P1f, const bf16_t* __restrict__ P2f,
    const bf16_t* __restrict__ P1r, const bf16_t* __restrict__ P2r,
    bf16_t* __restrict__ partial_f, bf16_t* __restrict__ partial_r,
    bf16_t* __restrict__ aggh_f, bf16_t* __restrict__ aggh_r)
{
  constexpr int CS = 264;
  __shared__ bf16_t Cs[64*CS];
  __shared__ int es[64], os[64], vs[64];
  const int tid = threadIdx.x;
  const int dir = blockIdx.x >> 12;
  const int tile = blockIdx.x & 4095;
  const int rb = tile*64;
  const int* eid  = dir ? eid_from  : eid_to;
  const int* oth  = dir ? to_idx    : from_idx;
  const int* rowv = dir ? rowv_from : rowv_to;
  const int* start= dir ? start_from: start_to;
  const bf16_t* P1 = dir ? P1r : P1f;
  const bf16_t* P2 = dir ? P2r : P2f;
  bf16_t* partial  = dir ? partial_r : partial_f;
  bf16_t* aggh     = dir ? aggh_r : aggh_f;
  const bf16_t* Wcd = Wc + (size_t)dir*16384;   // wcb part stride = 256*64 = 16384 elems

  if (tid < 64){
    int e = eid[rb + tid];
    es[tid] = e;
    os[tid] = oth[e];
    vs[tid] = rowv[rb + tid];
  }
  __syncthreads();

  const int lane = tid & 63, wave = tid >> 6, lr = lane & 15, lk = lane >> 4;
  {
    const float* arow = ef + (size_t)es[wave*16 + lr]*64;
    bf16x8 a0, a1;
    {
      f32x4 v0 = *(const f32x4*)(arow + lk*8);
      f32x4 v1 = *(const f32x4*)(arow + lk*8 + 4);
      a0 = cvt8(v0,v1);
      f32x4 w0 = *(const f32x4*)(arow + 32 + lk*8);
      f32x4 w1 = *(const f32x4*)(arow + 32 + lk*8 + 4);
      a1 = cvt8(w0,w1);
    }
    #pragma unroll
    for (int p=0;p<2;p++){
      f32x4 acc[8];
      #pragma unroll
      for (int nt=0;nt<8;nt++) acc[nt] = (f32x4){0.f,0.f,0.f,0.f};
      #pragma unroll
      for (int nt=0;nt<8;nt++){
        bf16x8 b0 = *(const bf16x8*)&Wcd[(size_t)((0*16 + p*8 + nt)*64 + lane)*8];
        acc[nt] = MFMA16(a0,b0,acc[nt]);
        bf16x8 b1v = *(const bf16x8*)&Wcd[(size_t)((1*16 + p*8 + nt)*64 + lane)*8];
        acc[nt] = MFMA16(a1,b1v,acc[nt]);
      }
      #pragma unroll
      for (int nt=0;nt<8;nt++)
        #pragma unroll
        for (int r=0;r<4;r++)
          Cs[(wave*16 + lk*4 + r)*CS + (p*8+nt)*16 + lr] = (bf16_t)acc[nt][r];
    }
  }
  __syncthreads();

  // phase 2a: vectorized branchless combine+relu (b1 already inside P2)
  const int c8 = (tid & 31) * 8;
  const int rbase = (tid >> 5) * 8;
  {
    #pragma unroll
    for (int j=0;j<8;j++){
      const int row = rbase + j;
      bf16x8 cs = *(const bf16x8*)&Cs[row*CS + c8];
      bf16x8 p1 = *(const bf16x8*)&P1[(size_t)os[row]*HH + c8];
      bf16x8 p2 = *(const bf16x8*)&P2[(size_t)vs[row]*HH + c8];
      bf16x8 o;
      #pragma unroll
      for (int k=0;k<8;k++)
        o[k] = (bf16_t)fmaxf((float)cs[k] + (float)p1[k] + (float)p2[k], 0.f);
      *(bf16x8*)&Cs[row*CS + c8] = o;
    }
  }
  __syncthreads();

  // phase 2b: LDS-only segmented sum (branch is block-uniform); tile-indexed partials
  const int c = tid;
  float runsum = 0.f;
  int curv = vs[0];
  for (int row=0; row<64; ++row){
    const int v = vs[row];
    if (v != curv){
      const int s0 = start[curv], s1 = start[curv+1];
      if (s0 >= rb && s1 <= rb+64)
        aggh[(size_t)curv*HH + c] = (bf16_t)runsum;
      else
        partial[((size_t)tile*2 + (s0 >= rb ? 1 : 0))*HH + c] = (bf16_t)runsum;
      runsum = 0.f; curv = v;
    }
    runsum += (float)Cs[row*CS + c];
  }
  {
    const int s0 = start[curv], s1 = start[curv+1];
    if (s0 >= rb && s1 <= rb+64)
      aggh[(size_t)curv*HH + c] = (bf16_t)runsum;
    else
      partial[((size_t)tile*2 + (s0 >= rb ? 1 : 0))*HH + c] = (bf16_t)runsum;
  }
}

// boundary node v (spans tiles t0,t0+1): aggh[v] = partial[t0][1] + partial[t0+1][0].
// deg-0: aggh[v]=0. grid (4096, 2): y=dir.
__global__ __launch_bounds__(256) void combine_kernel(
    const bf16_t* __restrict__ partial_f, const bf16_t* __restrict__ partial_r,
    const int* __restrict__ start_to, const int* __restrict__ start_from,
    bf16_t* __restrict__ aggh_f, bf16_t* __restrict__ aggh_r)
{
  const int dir = blockIdx.y;
  const bf16_t* partial = dir ? partial_r : partial_f;
  const int* start = dir ? start_from : start_to;
  bf16_t* aggh = dir ? aggh_r : aggh_f;
  const int tid = threadIdx.x;
  const int v = blockIdx.x*8 + (tid>>5);
  const int c0 = (tid & 31)*8;
  const int s0 = start[v], s1 = start[v+1];
  if (s1 == s0){
    bf16x8 z;
    #pragma unroll
    for (int j=0;j<8;j++) z[j] = (bf16_t)0.f;
    *(bf16x8*)&aggh[(size_t)v*HH + c0] = z;
  } else if ((s0>>6) != ((s1-1)>>6)){
    const int t0 = s0 >> 6;
    bf16x8 a = *(const bf16x8*)&partial[((size_t)t0*2 + 1)*HH + c0];
    bf16x8 b = *(const bf16x8*)&partial[((size_t)(t0+1)*2 + 0)*HH + c0];
    bf16x8 o;
    #pragma unroll
    for (int j=0;j<8;j++) o[j] = (bf16_t)((float)a[j] + (float)b[j]);
    *(bf16x8*)&aggh[(size_t)v*HH + c0] = o;
  }
}

// ---------------- weight prep for fused node MLP: w2t (blocks 0-31) + uw (block 32) ----------------
__global__ __launch_bounds__(256) void w2t_uw_kernel(const float* __restrict__ Wm2, const float* __restrict__ Wr2,
                                                     bf16_t* __restrict__ wm2T, bf16_t* __restrict__ wr2T,
                                                     const float* __restrict__ Wn1,
                                                     const float* __restrict__ bm2, const float* __restrict__ br2,
                                                     float* __restrict__ u, float* __restrict__ w){
  if (blockIdx.x == 32){
    const int n = threadIdx.x;
    float su=0.f, sw=0.f;
    for (int j=0;j<256;j+=4){
      f32x4 wv = *(const f32x4*)(Wn1 + (size_t)n*512 + j);
      f32x4 bu = *(const f32x4*)(bm2 + j);
      f32x4 bw = *(const f32x4*)(br2 + j);
      #pragma unroll
      for (int q=0;q<4;q++){ su += wv[q]*bu[q]; sw += wv[q]*bw[q]; }
    }
    u[n]=su; w[n]=sw;
    return;
  }
  __shared__ bf16_t t[64][72];
  const int bi = (blockIdx.x & 3)*64;
  const int bj = ((blockIdx.x>>2) & 3)*64;
  const int m  = blockIdx.x >> 4;
  const float* W = m ? Wr2 : Wm2;
  bf16_t* WT = m ? wr2T : wm2T;
  const int tid = threadIdx.x;
  #pragma unroll
  for (int it=0; it<16; ++it){
    int c = tid + it*256;
    int r = c >> 6, co = c & 63;
    t[r][co] = (bf16_t)W[(size_t)(bi+r)*256 + bj + co];
  }
  __syncthreads();
  #pragma unroll
  for (int it=0; it<16; ++it){
    int c = tid + it*256;
    int r = c >> 6, co = c & 63;
    WT[(size_t)(bj+r)*256 + bi + co] = t[co][r];
  }
}

// wcat: grid (4,3). cb<2: GEMM halves (proven). cb==2: copy Wn1[:,256:512] in tile order.
__global__ __launch_bounds__(256,2) void wcat_gemm_kernel(
    const float* __restrict__ Wn1, const bf16_t* __restrict__ wm2T, const bf16_t* __restrict__ wr2T,
    bf16_t* __restrict__ wcat)
{
  constexpr int XS = 264, CS = 264;
  const int tid = threadIdx.x;
  const int cb = blockIdx.y;
  if (cb == 2){
    #pragma unroll
    for (int it=0; it<8; ++it){
      int g = blockIdx.x*2048 + it*256 + tid;   // 8192 groups total
      int tile = g >> 6, lane = g & 63;
      int kc = tile >> 4, nt = tile & 15;
      int lr = lane & 15, lk = lane >> 4;
      int row = nt*16 + lr;
      int col = 256 + kc*32 + lk*8;
      f32x4 v0 = *(const f32x4*)(Wn1 + (size_t)row*512 + col);
      f32x4 v1 = *(const f32x4*)(Wn1 + (size_t)row*512 + col + 4);
      *(bf16x8*)&wcat[(size_t)(((16 + kc)*16 + nt)*64 + lane)*8] = cvt8(v0,v1);
    }
    return;
  }
  __shared__ bf16_t Xs[64*XS];
  __shared__ bf16_t Cs[64*CS];
  const int rb = blockIdx.x*64;
  const bf16_t* BT = cb ? wr2T : wm2T;
  #pragma unroll
  for (int it=0; it<16; ++it){
    int c = tid + it*256;
    int row = c >> 6, co = (c & 63)*4;
    f32x4 v = *(const f32x4*)(Wn1 + (size_t)(rb+row)*512 + co);
    bf16x4 o; o[0]=(bf16_t)v[0]; o[1]=(bf16_t)v[1]; o[2]=(bf16_t)v[2]; o[3]=(bf16_t)v[3];
    *(bf16x4*)&Xs[row*XS + co] = o;
  }
  __syncthreads();
  const int lane = tid & 63, wave = tid >> 6, lr = lane & 15, lk = lane >> 4;
  f32x4 acc[16];
  #pragma unroll
  for (int nt=0;nt<16;nt++) acc[nt] = (f32x4){0.f,0.f,0.f,0.f};
  #pragma unroll
  for (int kc=0;kc<8;kc++){
    bf16x8 a = *(const bf16x8*)&Xs[(wave*16 + lr)*XS + kc*32 + lk*8];
    #pragma unroll
    for (int nt=0;nt<16;nt++){
      bf16x8 b = *(const bf16x8*)&BT[(size_t)(nt*16 + lr)*256 + kc*32 + lk*8];
      acc[nt] = MFMA16(a,b,acc[nt]);
    }
  }
  #pragma unroll
  for (int nt=0;nt<16;nt++)
    #pragma unroll
    for (int r=0;r<4;r++)
      Cs[(wave*16 + lk*4 + r)*CS + nt*16 + lr] = (bf16_t)acc[nt][r];
  __syncthreads();
  const int nt_base = rb >> 4;
  #pragma unroll
  for (int it=0; it<8; ++it){
    int g = tid + it*256;
    int tile = g >> 6, lane2 = g & 63;
    int kc_l = tile >> 2, nt_l = tile & 3;
    int lr2 = lane2 & 15, lk2 = lane2 >> 4;
    bf16x8 v = *(const bf16x8*)&Cs[(nt_l*16 + lr2)*CS + kc_l*32 + lk2*8];
    *(bf16x8*)&wcat[(size_t)(((cb*8 + kc_l)*16 + nt_base + nt_l)*64 + lane2)*8] = v;
  }
}

// ---------------- nsT + nsB (proven round 14) ----------------
__global__ __launch_bounds__(256) void nst_kernel(const float* __restrict__ ns,
                                                  bf16_t* __restrict__ nsT,
                                                  bf16_t* __restrict__ nsB){
  constexpr int XS2 = 136;
  __shared__ bf16_t Xs[64*XS2];
  const int tid = threadIdx.x;
  const int nb = blockIdx.x*64;
  #pragma unroll
  for (int it=0; it<8; ++it){
    int c = tid + it*256;
    int rowl = c >> 5, co = (c & 31)*4;
    f32x4 v = *(const f32x4*)(ns + (size_t)(nb+rowl)*DD + co);
    bf16x4 o; o[0]=(bf16_t)v[0]; o[1]=(bf16_t)v[1]; o[2]=(bf16_t)v[2]; o[3]=(bf16_t)v[3];
    *(bf16x4*)&Xs[rowl*XS2 + co] = o;
    *(bf16x4*)&nsB[(size_t)(nb+rowl)*DD + co] = o;
  }
  __syncthreads();
  const int sb = nb >> 11;
  const int jb = nb & 2047;
  bf16_t* outp = nsT + (size_t)sb*DD*2048 + jb;
  #pragma unroll
  for (int it=0; it<4; ++it){
    int c = tid + it*256;
    int d = c >> 3, g8 = (c & 7)*8;
    bf16x8 o;
    #pragma unroll
    for (int k=0;k<8;k++){
      int s64 = g8 + k;
      int t32 = s64 >> 5, s = s64 & 31;
      int m = (s & 1) ? (16 + (s>>1)) : (s>>1);
      o[k] = Xs[(t32*32 + m)*XS2 + d];
    }
    *(bf16x8*)(outp + (size_t)d*2048 + g8) = o;
  }
}

// ---------------- cross-graph attention, KV-split (proven round 14; bf16 Opart) ----------------
__global__ __launch_bounds__(256,3) void attn_kernel(
    const bf16_t* __restrict__ nsB, const bf16_t* __restrict__ nsT,
    bf16_t* __restrict__ Opart, float* __restrict__ lpart)
{
  constexpr int KS = 136;
  constexpr int VS = 40;
  constexpr int PS = 40;
  __shared__ bf16_t Ks[2][32*KS];
  __shared__ bf16_t Vt[2][128*VS];
  __shared__ bf16_t Ps[64*PS];
  const int tid = threadIdx.x;
  const int lane = tid & 63, wave = tid >> 6, lr = lane & 15, lk = lane >> 4;
  const int bx = blockIdx.x;
  const int qt = bx & 31, side = (bx>>5)&1, p = (bx>>6)&7, kvh = bx>>9;
  const size_t qbase = (size_t)p*4096 + (size_t)side*2048 + (size_t)qt*64;
  const int sbkv = p*2 + (side^1);
  const bf16_t* Kv = nsB + ((size_t)p*4096 + (size_t)(side^1)*2048)*DD + (size_t)kvh*32*32*DD;
  const bf16_t* Vp = nsT + (size_t)sbkv*DD*2048 + (size_t)kvh*32*32;

  bf16x8 qf[4];
  {
    const bf16_t* qrow = nsB + (qbase + wave*16 + lr)*DD;
    #pragma unroll
    for (int kc=0;kc<4;kc++) qf[kc] = *(const bf16x8*)(qrow + kc*32 + lk*8);
  }
  float ls[4] = {0.f,0.f,0.f,0.f};
  f32x4 acco[8];
  #pragma unroll
  for (int nt=0;nt<8;nt++) acco[nt]=(f32x4){0.f,0.f,0.f,0.f};

  const int krow0 = tid>>4,        kcol = (tid&15)*8;
  const int vd0   = tid>>2,        vsl  = (tid&3)*8;
  bf16x8 kreg0, kreg1, vreg0, vreg1;

  auto load_tile = [&](int t){
    const bf16_t* kp = Kv + (size_t)t*32*DD;
    kreg0 = *(const bf16x8*)(kp + (size_t)krow0*DD + kcol);
    kreg1 = *(const bf16x8*)(kp + (size_t)(krow0+16)*DD + kcol);
    const bf16_t* vp = Vp + t*32;
    vreg0 = *(const bf16x8*)(vp + (size_t)vd0*2048 + vsl);
    vreg1 = *(const bf16x8*)(vp + (size_t)(vd0+64)*2048 + vsl);
  };
  auto store_tile = [&](int b){
    *(bf16x8*)&Ks[b][krow0*KS + kcol]      = kreg0;
    *(bf16x8*)&Ks[b][(krow0+16)*KS + kcol] = kreg1;
    *(bf16x8*)&Vt[b][vd0*VS + vsl]         = vreg0;
    *(bf16x8*)&Vt[b][(vd0+64)*VS + vsl]    = vreg1;
  };

  load_tile(0);
  store_tile(0);
  load_tile(1);
  __syncthreads();
  int cur = 0;
  for (int t=0; t<32; ++t){
    if (t+1 < 32){
      store_tile(cur^1);
      if (t+2 < 32) load_tile(t+2);
    }
    f32x4 s0 = (f32x4){0.f,0.f,0.f,0.f}, s1 = (f32x4){0.f,0.f,0.f,0.f};
    #pragma unroll
    for (int kc=0;kc<4;kc++){
      bf16x8 b0 = *(const bf16x8*)&Ks[cur][lr*KS      + kc*32 + lk*8];
      bf16x8 b1 = *(const bf16x8*)&Ks[cur][(16+lr)*KS + kc*32 + lk*8];
      s0 = MFMA16(qf[kc], b0, s0);
      s1 = MFMA16(qf[kc], b1, s1);
    }
    #pragma unroll
    for (int r=0;r<4;r++){
      float p0 = __expf(s0[r] - 40.f);
      float p1 = __expf(s1[r] - 40.f);
      ls[r] += p0 + p1;
      union { bf16_t h[2]; unsigned u; } pk;
      pk.h[0] = (bf16_t)p0; pk.h[1] = (bf16_t)p1;
      *(unsigned*)&Ps[(wave*16 + lk*4 + r)*PS + 2*lr] = pk.u;
    }
    asm volatile("s_waitcnt lgkmcnt(0)" ::: "memory");
    __builtin_amdgcn_sched_barrier(0);
    bf16x8 pa = *(const bf16x8*)&Ps[(wave*16 + lr)*PS + lk*8];
    #pragma unroll
    for (int nt=0;nt<8;nt++){
      bf16x8 vb = *(const bf16x8*)&Vt[cur][(nt*16+lr)*VS + lk*8];
      acco[nt] = MFMA16(pa, vb, acco[nt]);
    }
    __syncthreads();
    cur ^= 1;
  }
  #pragma unroll
  for (int r=0;r<4;r++){
    float v = ls[r];
    v += __shfl_xor(v,1); v += __shfl_xor(v,2);
    v += __shfl_xor(v,4); v += __shfl_xor(v,8);
    ls[r] = v;
  }
  bf16_t* Op = Opart + (size_t)kvh*NNODES*DD;
  #pragma unroll
  for (int r=0;r<4;r++){
    const size_t row = qbase + wave*16 + lk*4 + r;
    if (lr == 0) lpart[(size_t)kvh*NNODES + row] = ls[r];
    #pragma unroll
    for (int nt=0;nt<8;nt++)
      Op[row*DD + nt*16 + lr] = (bf16_t)acco[nt][r];
  }
}

// attnB = ns - (O0+O1)/(l0+l1)   (Opart stored bf16; O renormalized so 2^-8 rel err is fine)
__global__ __launch_bounds__(256) void attn_combine_kernel(
    const float* __restrict__ ns, const bf16_t* __restrict__ Opart,
    const float* __restrict__ lpart, bf16_t* __restrict__ attnB)
{
  const int tid = threadIdx.x;
  const int row = blockIdx.x*16 + (tid >> 4);
  const int c0 = (tid & 15)*8;
  const float inv = 1.f/(lpart[row] + lpart[NNODES + row]);
  bf16x8 a = *(const bf16x8*)&Opart[(size_t)row*DD + c0];
  bf16x8 b = *(const bf16x8*)&Opart[(size_t)NNODES*DD + (size_t)row*DD + c0];
  const float* nr = ns + (size_t)row*DD + c0;
  f32x4 n0 = *(const f32x4*)nr,      n1 = *(const f32x4*)(nr+4);
  bf16x8 o;
  #pragma unroll
  for (int j=0;j<4;j++){
    o[j]   = (bf16_t)(n0[j] - ((float)a[j]+(float)b[j])*inv);
    o[4+j] = (bf16_t)(n1[j] - ((float)a[4+j]+(float)b[4+j])*inv);
  }
  *(bf16x8*)&attnB[(size_t)row*DD + c0] = o;
}

// ---------------- fused node MLP + residual (proven round 9/13; 2 blocks/CU) ----------------
__global__ __launch_bounds__(256,2) void node_mlp_kernel(
    const bf16_t* __restrict__ agghf, const bf16_t* __restrict__ agghr,
    const bf16_t* __restrict__ attnB, const bf16_t* __restrict__ nsB,
    const float* __restrict__ ns,
    const bf16_t* __restrict__ wcat, const float* __restrict__ bn1,
    const float* __restrict__ uvec, const float* __restrict__ wvec,
    const int* __restrict__ start_to, const int* __restrict__ start_from,
    const bf16_t* __restrict__ Wn2b, const float* __restrict__ bn2,
    float* __restrict__ out)
{
  __shared__ __align__(16) bf16_t As[32*768];
  bf16_t* Hs = As;
  const int tid = threadIdx.x;
  const int lane = tid & 63, wave = tid >> 6, lr = lane & 15, lk = lane >> 4;
  const int rb = blockIdx.x*32;

  bf16x8 stg[12];
  int dsta[12];
  #pragma unroll
  for (int it=0; it<12; ++it){
    const int db = it*4096 + tid*16;
    const int row = db / 1536;
    const int within = db - row*1536;
    const size_t node = (size_t)(rb + row);
    const char* s0 = (const char*)agghf + (node<<9) + within;
    const char* s1 = (const char*)agghr + (node<<9) + (within-512);
    const char* s2 = (const char*)attnB + (node<<8) + (within-1024);
    const char* s3 = (const char*)nsB   + (node<<8) + (within-1280);
    const char* src = within < 512 ? s0 : (within < 1024 ? s1 : (within < 1280 ? s2 : s3));
    stg[it] = *(const bf16x8*)src;
    dsta[it] = row*1536 + (within ^ ((row & 7) << 4));
  }
  #pragma unroll
  for (int it=0; it<12; ++it)
    *(bf16x8*)((char*)As + dsta[it]) = stg[it];
  __syncthreads();

  const int cg = wave >> 1;
  const int colbase = cg * 128;
  const int arow = (wave & 1)*16 + lr;
  const unsigned abase = (unsigned)arow * 1536u;
  const unsigned asw = ((unsigned)(arow & 7)) << 4;
  f32x4 acc[8];
  #pragma unroll
  for (int nt=0;nt<8;nt++) acc[nt] = (f32x4){0.f,0.f,0.f,0.f};
  #pragma unroll
  for (int kc=0; kc<24; ++kc){
    const unsigned y = (unsigned)(kc*64 + lk*16);
    bf16x8 a = *(const bf16x8*)((const char*)As + abase + (y ^ asw));
    #pragma unroll
    for (int nt=0;nt<8;nt++){
      bf16x8 b = *(const bf16x8*)&wcat[(size_t)((kc*16 + cg*8 + nt)*64 + lane)*8];
      acc[nt] = MFMA16(a,b,acc[nt]);
    }
  }
  __syncthreads();

  const int r0 = rb + (wave&1)*16 + lk*4;
  float dt[4], df[4];
  #pragma unroll
  for (int r=0;r<4;r++){
    dt[r] = (float)(start_to[r0+r+1]   - start_to[r0+r]);
    df[r] = (float)(start_from[r0+r+1] - start_from[r0+r]);
  }
  #pragma unroll
  for (int nt=0;nt<8;nt++){
    const int col = colbase + nt*16 + lr;
    const float bias = bn1[col];
    const float uu = uvec[col], ww = wvec[col];
    #pragma unroll
    for (int r=0;r<4;r++){
      float v = acc[nt][r] + bias + dt[r]*uu + df[r]*ww;
      v = v > 0.f ? v : 0.f;
      Hs[((wave&1)*16 + lk*4 + r)*264 + col] = (bf16_t)v;
    }
  }
  __syncthreads();

  const int cb2 = cg * 64;
  f32x4 acc2[4];
  #pragma unroll
  for (int nt=0;nt<4;nt++) acc2[nt] = (f32x4){0.f,0.f,0.f,0.f};
  #pragma unroll
  for (int kc=0;kc<8;kc++){
    bf16x8 a = *(const bf16x8*)&Hs[((wave&1)*16 + lr)*264 + kc*32 + lk*8];
    #pragma unroll
    for (int nt=0;nt<4;nt++){
      bf16x8 b = *(const bf16x8*)&Wn2b[(size_t)((kc*8 + cg*4 + nt)*64 + lane)*8];
      acc2[nt] = MFMA16(a,b,acc2[nt]);
    }
  }
  #pragma unroll
  for (int nt=0;nt<4;nt++){
    const int col = cb2 + nt*16 + lr;
    const float bias = bn2[col];
    #pragma unroll
    for (int r=0;r<4;r++){
      const size_t rr = (size_t)(r0 + r);
      out[rr*DD + col] = acc2[nt][r] + bias + ns[rr*DD + col];
    }
  }
}

extern "C" void kernel_launch(void* const* d_in, const int* in_sizes, int n_in,
                              void* d_out, int out_size, void* d_ws, size_t ws_size,
                              hipStream_t stream) {
  const float* ns  = (const float*)d_in[0];
  const float* ef  = (const float*)d_in[1];
  const int* from_idx = (const int*)d_in[2];
  const int* to_idx   = (const int*)d_in[3];
  const float* Wm1 = (const float*)d_in[6];  const float* bm1 = (const float*)d_in[7];
  const float* Wm2 = (const float*)d_in[8];  const float* bm2 = (const float*)d_in[9];
  const float* Wr1 = (const float*)d_in[10]; const float* br1 = (const float*)d_in[11];
  const float* Wr2 = (const float*)d_in[12]; const float* br2 = (const float*)d_in[13];
  const float* Wn1 = (const float*)d_in[14]; const float* bn1 = (const float*)d_in[15];
  const float* Wn2 = (const float*)d_in[16]; const float* bn2 = (const float*)d_in[17];

  char* ws = (char*)d_ws;
  // ---- phase-1 region (0..134 MB) ----
  bf16_t* partial_f = (bf16_t*)(ws);                   // 4,194,304 (tile-indexed)
  bf16_t* partial_r = (bf16_t*)(ws + 4194304);         // 4,194,304 (ends 8,388,608)
  int*    rowv_to   = (int*)(ws + 41943040);           // 1 MB
  int*    rowv_from = (int*)(ws + 42991616);           // 1 MB (ends 44,040,192)
  bf16_t* P1r   = (bf16_t*)(ws + 44040192);            // 16,777,216
  bf16_t* P2r   = (bf16_t*)(ws + 60817408);            // 16,777,216 (ends 77,594,624)
  bf16_t* P1f   = (bf16_t*)(ws + 134217728);
  bf16_t* P2f   = (bf16_t*)(ws + 150994944);
  bf16_t* aggh_f = (bf16_t*)(ws + 167772160);
  bf16_t* aggh_r = (bf16_t*)(ws + 184549376);
  bf16_t* wpb  = (bf16_t*)(ws + 201326592);
  bf16_t* wcb  = (bf16_t*)(ws + 201588736);
  bf16_t* wn2b = (bf16_t*)(ws + 201654272);
  int* cur_to     = (int*)(ws + 202244096);
  int* cur_from   = (int*)(ws + 202375168);
  int* start_to   = (int*)(ws + 202506240);
  int* start_from = (int*)(ws + 202637320);
  int* eid_to     = (int*)(ws + 202768400);
  int* eid_from   = (int*)(ws + 203816976);
  // ---- phase-2 overlays (all producers run after combine; overlapped regions dead) ----
  bf16_t* attnB = (bf16_t*)(ws);                       // 8 MB over dead partials
  bf16_t* nsB   = (bf16_t*)(ws + 33554432);            // 8 MB
  bf16_t* nsT   = (bf16_t*)(ws + 41943040);            // 8 MB over dead rowv/P1r-head
  bf16_t* wm2T  = (bf16_t*)(ws + 50331648);            // 128 KB (dead P1r)
  bf16_t* wr2T  = (bf16_t*)(ws + 50462720);            // 128 KB
  bf16_t* wcat  = (bf16_t*)(ws + 50593792);            // 384 KB
  float*  uvec  = (float*) (ws + 50987008);            // 1 KB
  float*  wvec  = (float*) (ws + 50988032);            // 1 KB
  bf16_t* Opart = (bf16_t*)(ws + 69206016);            // 16 MB over dead P2r (bf16)
  float*  lpart = (float*) (ws + 102760448);           // 256 KB

  hipMemsetAsync(cur_to, 0, 2*NNODES*sizeof(int), stream);

  pack_weights_kernel<<<160, 256, 0, stream>>>(Wm1, Wr1, Wn2, wpb, wcb, wn2b);

  hist_kernel<<<NEDGES/256, 256, 0, stream>>>(to_idx, from_idx, cur_to, cur_from);
  scan_kernel<<<2, 1024, 0, stream>>>(cur_to, cur_from, start_to, start_from);
  place_kernel<<<NEDGES/256, 256, 0, stream>>>(to_idx, from_idx, cur_to, cur_from,
      eid_to, eid_from, rowv_to, rowv_from);

  // both direction projections in one dispatch (b1 folded into P2)
  proj_kernel<<<dim3(NNODES/64, 2, 2), 256, 0, stream>>>(ns, wpb, bm1, br1,
      P1f, P2f, P1r, P2r);

  // both direction fused edge passes in one dispatch (f32 ef gather, in-kernel cvt)
  edge_agg_kernel<<<2*NEDGES/64, 256, 0, stream>>>(ef, wcb,
      eid_to, eid_from, from_idx, to_idx, rowv_to, rowv_from, start_to, start_from,
      P1f, P2f, P1r, P2r, partial_f, partial_r, aggh_f, aggh_r);

  combine_kernel<<<dim3(NNODES/8, 2), 256, 0, stream>>>(partial_f, partial_r,
      start_to, start_from, aggh_f, aggh_r);

  // phase 2 prep
  nst_kernel<<<NNODES/64, 256, 0, stream>>>(ns, nsT, nsB);
  w2t_uw_kernel<<<33, 256, 0, stream>>>(Wm2, Wr2, wm2T, wr2T, Wn1, bm2, br2, uvec, wvec);
  wcat_gemm_kernel<<<dim3(4,3), 256, 0, stream>>>(Wn1, wm2T, wr2T, wcat);

  attn_kernel<<<1024, 256, 0, stream>>>(nsB, nsT, Opart, lpart);
  attn_combine_kernel<<<NNODES/16, 256, 0, stream>>>(ns, Opart, lpart, attnB);

  node_mlp_kernel<<<NNODES/32, 256, 0, stream>>>(aggh_f, aggh_r, attnB, nsB, ns,
      wcat, bn1, uvec, wvec, start_to, start_from, wn2b, bn2, (float*)d_out);
}